// Round 1
// baseline (2268.521 us; speedup 1.0000x reference)
//
#include <hip/hip_runtime.h>
#include <hip/hip_bf16.h>
#include <cstddef>

#define NM 50000
#define NA 50000
#define ND 500
#define FEAT 128
#define KDIM 768
#define BATCH 1024
#define NEDGE 1600000
#define NNODES 100000
#define NPARTS 391   // ceil(100000/256)

__device__ __forceinline__ float sigf(float x) { return 1.0f / (1.0f + __expf(-x)); }

// ---------------- projection: C = sigmoid(A[M,768] @ W[768,128] + b) ----------------
// BM=64 rows/block, 256 threads, thread tile 8 rows x 4 cols, BK=32.
#define PBM 64
#define PBK 32
__global__ __launch_bounds__(256) void proj_kernel(
    const float* __restrict__ A, const float* __restrict__ W,
    const float* __restrict__ bias, float* __restrict__ C, int M,
    float* __restrict__ C2 /* optional: 0.25*sigmoid for out_api init */)
{
  __shared__ float As[PBK][PBM + 4];   // [k][row], row stride 68 (16B aligned, bank-spread)
  __shared__ float Ws[PBK][FEAT + 4];  // [k][col], row stride 132
  const int tid = threadIdx.x;
  const int rowBase = blockIdx.x * PBM;
  const int tr = tid >> 5;   // 0..7  -> rows 8*tr..8*tr+7
  const int tc = tid & 31;   // 0..31 -> cols 4*tc..4*tc+3
  float acc[8][4];
  #pragma unroll
  for (int a = 0; a < 8; ++a)
    #pragma unroll
    for (int b = 0; b < 4; ++b) acc[a][b] = 0.f;

  for (int k0 = 0; k0 < KDIM; k0 += PBK) {
    // stage A tile (64x32), transposed into [k][row]
    #pragma unroll
    for (int it = 0; it < 2; ++it) {
      int flat = tid + 256 * it;
      int r = flat >> 3;
      int kq = (flat & 7) << 2;
      int rg = rowBase + r; rg = rg < M ? rg : (M - 1);
      float4 v = *(const float4*)(A + (size_t)rg * KDIM + k0 + kq);
      As[kq + 0][r] = v.x; As[kq + 1][r] = v.y;
      As[kq + 2][r] = v.z; As[kq + 3][r] = v.w;
    }
    // stage W tile (32x128)
    #pragma unroll
    for (int it = 0; it < 4; ++it) {
      int flat = tid + 256 * it;
      int k = flat >> 5;
      int cq = (flat & 31) << 2;
      float4 v = *(const float4*)(W + (size_t)(k0 + k) * FEAT + cq);
      *(float4*)&Ws[k][cq] = v;
    }
    __syncthreads();
    #pragma unroll 8
    for (int kk = 0; kk < PBK; ++kk) {
      float4 a0 = *(const float4*)&As[kk][tr * 8];
      float4 a1 = *(const float4*)&As[kk][tr * 8 + 4];
      float4 w  = *(const float4*)&Ws[kk][tc * 4];
      float av[8] = {a0.x, a0.y, a0.z, a0.w, a1.x, a1.y, a1.z, a1.w};
      float wv[4] = {w.x, w.y, w.z, w.w};
      #pragma unroll
      for (int j = 0; j < 8; ++j)
        #pragma unroll
        for (int l = 0; l < 4; ++l) acc[j][l] += av[j] * wv[l];
    }
    __syncthreads();
  }
  float4 bv = *(const float4*)(bias + tc * 4);
  #pragma unroll
  for (int j = 0; j < 8; ++j) {
    int r = rowBase + tr * 8 + j;
    if (r < M) {
      float4 o;
      o.x = sigf(acc[j][0] + bv.x);
      o.y = sigf(acc[j][1] + bv.y);
      o.z = sigf(acc[j][2] + bv.z);
      o.w = sigf(acc[j][3] + bv.w);
      *(float4*)(C + (size_t)r * FEAT + tc * 4) = o;
      if (C2) {
        float4 o2; o2.x = 0.25f * o.x; o2.y = 0.25f * o.y;
        o2.z = 0.25f * o.z; o2.w = 0.25f * o.w;
        *(float4*)(C2 + (size_t)r * FEAT + tc * 4) = o2;
      }
    }
  }
}

// ---------------- attention: al = v_mi@v_key^T ; alpha=al/rowsum ; z = 0.5*(alpha@v_val) + 0.5*v_mi
__global__ __launch_bounds__(256) void attn_kernel(
    const float* __restrict__ vmi, const float* __restrict__ vkey,
    const float* __restrict__ vval, float* __restrict__ zm)
{
  const int i = blockIdx.x;
  const int tid = threadIdx.x;
  __shared__ float vs[FEAT];
  __shared__ float al[ND];
  __shared__ float red[4];
  __shared__ float totS;
  if (tid < FEAT) vs[tid] = vmi[(size_t)i * FEAT + tid];
  __syncthreads();
  float part = 0.f;
  for (int j = tid; j < ND; j += 256) {
    const float* kr = vkey + (size_t)j * FEAT;
    float dot = 0.f;
    #pragma unroll 8
    for (int k = 0; k < FEAT; k += 4) {
      float4 kv = *(const float4*)(kr + k);
      dot += vs[k] * kv.x + vs[k + 1] * kv.y + vs[k + 2] * kv.z + vs[k + 3] * kv.w;
    }
    al[j] = dot;
    part += dot;
  }
  #pragma unroll
  for (int o = 32; o > 0; o >>= 1) part += __shfl_down(part, o, 64);
  if ((tid & 63) == 0) red[tid >> 6] = part;
  __syncthreads();
  if (tid == 0) totS = red[0] + red[1] + red[2] + red[3];
  __syncthreads();
  const float inv = 1.0f / totS;
  if (tid < FEAT) {
    float s = 0.f;
    #pragma unroll 4
    for (int j = 0; j < ND; ++j) s += al[j] * vval[(size_t)j * FEAT + tid];
    float z = 0.5f * (s * inv + vs[tid]);
    zm[(size_t)i * FEAT + tid] = z;
  }
}

// ---------------- degree histogram ----------------
__global__ void hist_kernel(const int* __restrict__ src, const int* __restrict__ dst,
                            int* __restrict__ deg)
{
  int stride = gridDim.x * blockDim.x;
  for (int e = blockIdx.x * blockDim.x + threadIdx.x; e < NEDGE; e += stride) {
    atomicAdd(&deg[src[e]], 1);
    atomicAdd(&deg[NM + dst[e]], 1);
  }
}

// ---------------- scan step A: per-block sums ----------------
__global__ __launch_bounds__(256) void scan_blocksum(const int* __restrict__ deg,
                                                     int* __restrict__ parts)
{
  int i = blockIdx.x * 256 + threadIdx.x;
  int v = (i < NNODES) ? deg[i] : 0;
  __shared__ int red[4];
  #pragma unroll
  for (int o = 32; o > 0; o >>= 1) v += __shfl_down(v, o, 64);
  if ((threadIdx.x & 63) == 0) red[threadIdx.x >> 6] = v;
  __syncthreads();
  if (threadIdx.x == 0) parts[blockIdx.x] = red[0] + red[1] + red[2] + red[3];
}

// ---------------- scan step B: exclusive scan of partials (1 block) ----------------
__global__ __launch_bounds__(512) void scan_parts(int* __restrict__ parts)
{
  __shared__ int s[512];
  int t = threadIdx.x;
  int v = (t < NPARTS) ? parts[t] : 0;
  s[t] = v;
  __syncthreads();
  for (int o = 1; o < 512; o <<= 1) {
    int x = (t >= o) ? s[t - o] : 0;
    __syncthreads();
    s[t] += x;
    __syncthreads();
  }
  if (t < NPARTS) parts[t] = s[t] - v;  // exclusive
}

// ---------------- scan step C: final offsets + cursor + dinv ----------------
__global__ __launch_bounds__(256) void scan_final(const int* __restrict__ deg,
                                                  const int* __restrict__ parts,
                                                  int* __restrict__ offs,
                                                  int* __restrict__ curs,
                                                  float* __restrict__ dinv)
{
  __shared__ int s[256];
  int t = threadIdx.x;
  int i = blockIdx.x * 256 + t;
  int v = (i < NNODES) ? deg[i] : 0;
  s[t] = v;
  __syncthreads();
  for (int o = 1; o < 256; o <<= 1) {
    int x = (t >= o) ? s[t - o] : 0;
    __syncthreads();
    s[t] += x;
    __syncthreads();
  }
  if (i < NNODES) {
    int off = parts[blockIdx.x] + s[t] - v;
    offs[i] = off;
    curs[i] = off;
    dinv[i] = (v > 0) ? rsqrtf((float)v) : 0.f;
  }
  if (i == 0) offs[NNODES] = 2 * NEDGE;
}

// ---------------- CSR adjacency fill ----------------
__global__ void fill_kernel(const int* __restrict__ src, const int* __restrict__ dst,
                            int* __restrict__ curs, int* __restrict__ adj)
{
  int stride = gridDim.x * blockDim.x;
  for (int e = blockIdx.x * blockDim.x + threadIdx.x; e < NEDGE; e += stride) {
    int s = src[e];
    int d = NM + dst[e];
    adj[atomicAdd(&curs[d], 1)] = s;  // node d gathers from s
    adj[atomicAdd(&curs[s], 1)] = d;  // node s gathers from d
  }
}

// ---------------- LightGCN propagation (gather form), fused out_api accumulation ----
__global__ __launch_bounds__(256) void prop_kernel(
    const float* __restrict__ xin, float* __restrict__ xout,
    const int* __restrict__ offs, const int* __restrict__ adj,
    const float* __restrict__ dinv, float* __restrict__ outA)
{
  const int v = blockIdx.x * 4 + (threadIdx.x >> 6);  // one wave per node
  const int lane = threadIdx.x & 63;
  int p = offs[v];
  const int p1 = offs[v + 1];
  float ax = 0.f, ay = 0.f;
  const float* base = xin + 2 * lane;
  for (; p + 2 <= p1; p += 2) {
    int u0 = adj[p], u1 = adj[p + 1];
    float d0 = dinv[u0], d1 = dinv[u1];
    float2 r0 = *(const float2*)(base + (size_t)u0 * FEAT);
    float2 r1 = *(const float2*)(base + (size_t)u1 * FEAT);
    ax += r0.x * d0 + r1.x * d1;
    ay += r0.y * d0 + r1.y * d1;
  }
  if (p < p1) {
    int u0 = adj[p];
    float d0 = dinv[u0];
    float2 r0 = *(const float2*)(base + (size_t)u0 * FEAT);
    ax += r0.x * d0;
    ay += r0.y * d0;
  }
  const float dv = dinv[v];
  float2 res; res.x = ax * dv; res.y = ay * dv;
  *(float2*)(xout + (size_t)v * FEAT + 2 * lane) = res;
  if (v >= NM) {
    float2* o = (float2*)(outA + (size_t)(v - NM) * FEAT + 2 * lane);
    float2 c = *o;
    c.x += 0.25f * res.x;
    c.y += 0.25f * res.y;
    *o = c;
  }
}

// ---------------- pred = z_m[1024,128] @ O[50000,128]^T ----------------
#define QBM 32
#define QBN 64
__global__ __launch_bounds__(256) void pred_kernel(
    const float* __restrict__ zm, const float* __restrict__ O, float* __restrict__ out)
{
  __shared__ float Zs[FEAT][QBM + 4];  // [k][i], stride 36
  __shared__ float Os[FEAT][QBN + 4];  // [k][n], stride 68
  const int tid = threadIdx.x;
  const int nBase = blockIdx.x * QBN;
  const int iBase = blockIdx.y * QBM;
  #pragma unroll
  for (int it = 0; it < 4; ++it) {
    int flat = tid + 256 * it;
    int r = flat >> 5;
    int kq = (flat & 31) << 2;
    float4 v = *(const float4*)(zm + (size_t)(iBase + r) * FEAT + kq);
    Zs[kq + 0][r] = v.x; Zs[kq + 1][r] = v.y; Zs[kq + 2][r] = v.z; Zs[kq + 3][r] = v.w;
  }
  #pragma unroll
  for (int it = 0; it < 8; ++it) {
    int flat = tid + 256 * it;
    int n = flat >> 5;
    int kq = (flat & 31) << 2;
    int ng = nBase + n;
    float4 v = make_float4(0.f, 0.f, 0.f, 0.f);
    if (ng < NA) v = *(const float4*)(O + (size_t)ng * FEAT + kq);
    Os[kq + 0][n] = v.x; Os[kq + 1][n] = v.y; Os[kq + 2][n] = v.z; Os[kq + 3][n] = v.w;
  }
  __syncthreads();
  const int i4 = tid >> 5;  // 0..7 -> rows 4*i4..4*i4+3
  const int nh = tid & 31;  // 0..31 -> cols 2*nh, 2*nh+1
  float acc[4][2];
  #pragma unroll
  for (int j = 0; j < 4; ++j) { acc[j][0] = 0.f; acc[j][1] = 0.f; }
  #pragma unroll 4
  for (int k = 0; k < FEAT; ++k) {
    float4 zv = *(const float4*)&Zs[k][i4 * 4];
    float2 ov = *(const float2*)&Os[k][nh * 2];
    float zz[4] = {zv.x, zv.y, zv.z, zv.w};
    #pragma unroll
    for (int j = 0; j < 4; ++j) {
      acc[j][0] += zz[j] * ov.x;
      acc[j][1] += zz[j] * ov.y;
    }
  }
  const int ng = nBase + nh * 2;
  if (ng < NA) {
    #pragma unroll
    for (int j = 0; j < 4; ++j) {
      int ig = iBase + i4 * 4 + j;
      float2 r; r.x = acc[j][0]; r.y = acc[j][1];
      *(float2*)(out + (size_t)ig * NA + ng) = r;
    }
  }
}

extern "C" void kernel_launch(void* const* d_in, const int* in_sizes, int n_in,
                              void* d_out, int out_size, void* d_ws, size_t ws_size,
                              hipStream_t stream) {
  const float* x      = (const float*)d_in[0];
  const float* mashup = (const float*)d_in[1];
  const float* domain = (const float*)d_in[2];
  const float* api    = (const float*)d_in[3];
  const float* Wsde   = (const float*)d_in[4];
  const float* bsde   = (const float*)d_in[5];
  const float* Wval   = (const float*)d_in[6];
  const float* bval   = (const float*)d_in[7];
  const float* Wkey   = (const float*)d_in[8];
  const float* bkey   = (const float*)d_in[9];
  const float* Wsie   = (const float*)d_in[10];
  const float* bsie   = (const float*)d_in[11];
  const int* esrc     = (const int*)d_in[12];
  const int* edst     = (const int*)d_in[13];
  float* out = (float*)d_out;

  // workspace layout (fp32 elements)
  float* ws   = (float*)d_ws;
  float* embA = ws;                                  // 100000*128
  float* embB = embA + (size_t)NNODES * FEAT;        // 100000*128
  float* outA = embB + (size_t)NNODES * FEAT;        // 50000*128
  float* vmi  = outA + (size_t)NA * FEAT;            // 1024*128
  float* vkey = vmi + (size_t)BATCH * FEAT;          // 500*128
  float* vval = vkey + (size_t)ND * FEAT;            // 500*128
  float* zm   = vval + (size_t)ND * FEAT;            // 1024*128
  float* dinv = zm + (size_t)BATCH * FEAT;           // 100000
  int* deg    = (int*)(dinv + NNODES);               // 100000
  int* offs   = deg + NNODES;                        // 100001
  int* curs   = offs + NNODES + 1;                   // 100000
  int* adj    = curs + NNODES;                       // 3200000
  int* parts  = adj + 2 * NEDGE;                     // 391

  hipMemsetAsync(deg, 0, NNODES * sizeof(int), stream);

  proj_kernel<<<(BATCH + PBM - 1) / PBM, 256, 0, stream>>>(x, Wsde, bsde, vmi, BATCH, nullptr);
  proj_kernel<<<(ND + PBM - 1) / PBM, 256, 0, stream>>>(domain, Wkey, bkey, vkey, ND, nullptr);
  proj_kernel<<<(ND + PBM - 1) / PBM, 256, 0, stream>>>(domain, Wval, bval, vval, ND, nullptr);
  attn_kernel<<<BATCH, 256, 0, stream>>>(vmi, vkey, vval, zm);

  proj_kernel<<<(NM + PBM - 1) / PBM, 256, 0, stream>>>(mashup, Wsde, bsde, embA, NM, nullptr);
  proj_kernel<<<(NA + PBM - 1) / PBM, 256, 0, stream>>>(api, Wsie, bsie,
                                                        embA + (size_t)NM * FEAT, NA, outA);

  hist_kernel<<<2048, 256, 0, stream>>>(esrc, edst, deg);
  scan_blocksum<<<NPARTS, 256, 0, stream>>>(deg, parts);
  scan_parts<<<1, 512, 0, stream>>>(parts);
  scan_final<<<NPARTS, 256, 0, stream>>>(deg, parts, offs, curs, dinv);
  fill_kernel<<<2048, 256, 0, stream>>>(esrc, edst, curs, adj);

  prop_kernel<<<NNODES / 4, 256, 0, stream>>>(embA, embB, offs, adj, dinv, outA);
  prop_kernel<<<NNODES / 4, 256, 0, stream>>>(embB, embA, offs, adj, dinv, outA);
  prop_kernel<<<NNODES / 4, 256, 0, stream>>>(embA, embB, offs, adj, dinv, outA);

  pred_kernel<<<dim3((NA + QBN - 1) / QBN, BATCH / QBM), 256, 0, stream>>>(zm, outA, out);
}

// Round 2
// 1563.590 us; speedup vs baseline: 1.4508x; 1.4508x over previous
//
#include <hip/hip_runtime.h>
#include <hip/hip_bf16.h>
#include <cstddef>

#define NM 50000
#define NA 50000
#define ND 500
#define FEAT 128
#define KDIM 768
#define BATCH 1024
#define NEDGE 1600000
#define NNODES 100000
#define NPARTS 391   // ceil(100000/256)

typedef __bf16 bf16_t;
typedef bf16_t bf16x8 __attribute__((ext_vector_type(8)));
typedef float f32x4 __attribute__((ext_vector_type(4)));

__device__ __forceinline__ float sigf(float x) { return 1.0f / (1.0f + __expf(-x)); }

// ---------------- W[768,128] fp32 -> Wt[128,768] bf16 ----------------
__global__ __launch_bounds__(256) void wconv_kernel(const float* __restrict__ W,
                                                    bf16_t* __restrict__ Wt)
{
  int c = blockIdx.x;
  for (int k = threadIdx.x; k < KDIM; k += 256)
    Wt[(size_t)c * KDIM + k] = (bf16_t)W[(size_t)k * FEAT + c];
}

// ---------------- projection via MFMA: C = sigmoid(A[M,768] @ W[768,128] + b) ----
// BM=128, BN=128(full), BK=32, 4 waves (2x2), each wave 64x64 via 4x4 frags of 16x16x32.
// LDS: fragment-major layout, lane-linear ds_read_b128 (conflict-free).
__global__ __launch_bounds__(256) void proj_mfma(
    const float* __restrict__ A, const bf16_t* __restrict__ Wt,
    const float* __restrict__ bias, float* __restrict__ C, int M,
    float* __restrict__ C2 /* optional 0.25*sigmoid copy */)
{
  __shared__ bf16x8 sm[1024];  // [0..511]=A frags (8KB), [512..1023]=B frags (8KB)
  const int tid = threadIdx.x;
  const int rowBase = blockIdx.x * 128;
  const int lane = tid & 63;
  const int wid = tid >> 6;

  f32x4 acc[4][4];
  #pragma unroll
  for (int m = 0; m < 4; ++m)
    #pragma unroll
    for (int n = 0; n < 4; ++n)
      acc[m][n] = (f32x4){0.f, 0.f, 0.f, 0.f};

  // staging mapping: thread t, iter i: frag f=(t>>6)+4i, rloc=f*16+(t&15), k8=(t>>4)&3
  // LDS slot = t + 256*i  (identity: slot>>6 = f, slot&63 = (k8<<4)|(t&15))
  const int rl0 = ((tid >> 6) << 4) + (tid & 15);
  const int k8 = (tid >> 4) & 3;

  for (int k0 = 0; k0 < KDIM; k0 += 32) {
    #pragma unroll
    for (int i = 0; i < 2; ++i) {
      int rloc = rl0 + 64 * i;
      int rg = rowBase + rloc;
      if (rg > M - 1) rg = M - 1;
      const float* ap = A + (size_t)rg * KDIM + k0 + k8 * 8;
      float4 v0 = *(const float4*)ap;
      float4 v1 = *(const float4*)(ap + 4);
      bf16x8 w;
      w[0] = (bf16_t)v0.x; w[1] = (bf16_t)v0.y; w[2] = (bf16_t)v0.z; w[3] = (bf16_t)v0.w;
      w[4] = (bf16_t)v1.x; w[5] = (bf16_t)v1.y; w[6] = (bf16_t)v1.z; w[7] = (bf16_t)v1.w;
      sm[tid + i * 256] = w;
      // B: Wt[col][k] bf16, col = rloc (<128), 8 consecutive k = 16B
      sm[512 + tid + i * 256] = *(const bf16x8*)(Wt + (size_t)rloc * KDIM + k0 + k8 * 8);
    }
    __syncthreads();
    bf16x8 a[4], b[4];
    const int fm = (wid >> 1) * 4, fn = (wid & 1) * 4;
    #pragma unroll
    for (int m = 0; m < 4; ++m) a[m] = sm[(fm + m) * 64 + lane];
    #pragma unroll
    for (int n = 0; n < 4; ++n) b[n] = sm[512 + (fn + n) * 64 + lane];
    #pragma unroll
    for (int m = 0; m < 4; ++m)
      #pragma unroll
      for (int n = 0; n < 4; ++n)
        acc[m][n] = __builtin_amdgcn_mfma_f32_16x16x32_bf16(a[m], b[n], acc[m][n], 0, 0, 0);
    __syncthreads();
  }

  // epilogue: C frag layout col=lane&15, row=(lane>>4)*4+reg  [m89-verified]
  const int wRow = (wid >> 1) * 64, wCol = (wid & 1) * 64;
  const int r0 = (lane >> 4) * 4, cc = lane & 15;
  #pragma unroll
  for (int n = 0; n < 4; ++n) {
    int col = wCol + n * 16 + cc;
    float bb = bias[col];
    #pragma unroll
    for (int m = 0; m < 4; ++m) {
      #pragma unroll
      for (int r = 0; r < 4; ++r) {
        int row = rowBase + wRow + m * 16 + r0 + r;
        if (row < M) {
          float v = sigf(acc[m][n][r] + bb);
          C[(size_t)row * FEAT + col] = v;
          if (C2) C2[(size_t)row * FEAT + col] = 0.25f * v;
        }
      }
    }
  }
}

// ---------------- attention: al = v_mi@v_key^T ; alpha=al/rowsum ; z = 0.5*(alpha@v_val) + 0.5*v_mi
__global__ __launch_bounds__(256) void attn_kernel(
    const float* __restrict__ vmi, const float* __restrict__ vkey,
    const float* __restrict__ vval, float* __restrict__ zm)
{
  const int i = blockIdx.x;
  const int tid = threadIdx.x;
  __shared__ float vs[FEAT];
  __shared__ float al[ND];
  __shared__ float red[4];
  __shared__ float totS;
  if (tid < FEAT) vs[tid] = vmi[(size_t)i * FEAT + tid];
  __syncthreads();
  float part = 0.f;
  for (int j = tid; j < ND; j += 256) {
    const float* kr = vkey + (size_t)j * FEAT;
    float dot = 0.f;
    #pragma unroll 8
    for (int k = 0; k < FEAT; k += 4) {
      float4 kv = *(const float4*)(kr + k);
      dot += vs[k] * kv.x + vs[k + 1] * kv.y + vs[k + 2] * kv.z + vs[k + 3] * kv.w;
    }
    al[j] = dot;
    part += dot;
  }
  #pragma unroll
  for (int o = 32; o > 0; o >>= 1) part += __shfl_down(part, o, 64);
  if ((tid & 63) == 0) red[tid >> 6] = part;
  __syncthreads();
  if (tid == 0) totS = red[0] + red[1] + red[2] + red[3];
  __syncthreads();
  const float inv = 1.0f / totS;
  if (tid < FEAT) {
    float s = 0.f;
    #pragma unroll 4
    for (int j = 0; j < ND; ++j) s += al[j] * vval[(size_t)j * FEAT + tid];
    float z = 0.5f * (s * inv + vs[tid]);
    zm[(size_t)i * FEAT + tid] = z;
  }
}

// ---------------- degree histogram ----------------
__global__ void hist_kernel(const int* __restrict__ src, const int* __restrict__ dst,
                            int* __restrict__ deg)
{
  int stride = gridDim.x * blockDim.x;
  for (int e = blockIdx.x * blockDim.x + threadIdx.x; e < NEDGE; e += stride) {
    atomicAdd(&deg[src[e]], 1);
    atomicAdd(&deg[NM + dst[e]], 1);
  }
}

// ---------------- scan step A ----------------
__global__ __launch_bounds__(256) void scan_blocksum(const int* __restrict__ deg,
                                                     int* __restrict__ parts)
{
  int i = blockIdx.x * 256 + threadIdx.x;
  int v = (i < NNODES) ? deg[i] : 0;
  __shared__ int red[4];
  #pragma unroll
  for (int o = 32; o > 0; o >>= 1) v += __shfl_down(v, o, 64);
  if ((threadIdx.x & 63) == 0) red[threadIdx.x >> 6] = v;
  __syncthreads();
  if (threadIdx.x == 0) parts[blockIdx.x] = red[0] + red[1] + red[2] + red[3];
}

// ---------------- scan step B ----------------
__global__ __launch_bounds__(512) void scan_parts(int* __restrict__ parts)
{
  __shared__ int s[512];
  int t = threadIdx.x;
  int v = (t < NPARTS) ? parts[t] : 0;
  s[t] = v;
  __syncthreads();
  for (int o = 1; o < 512; o <<= 1) {
    int x = (t >= o) ? s[t - o] : 0;
    __syncthreads();
    s[t] += x;
    __syncthreads();
  }
  if (t < NPARTS) parts[t] = s[t] - v;  // exclusive
}

// ---------------- scan step C ----------------
__global__ __launch_bounds__(256) void scan_final(const int* __restrict__ deg,
                                                  const int* __restrict__ parts,
                                                  int* __restrict__ offs,
                                                  int* __restrict__ curs,
                                                  float* __restrict__ dinv)
{
  __shared__ int s[256];
  int t = threadIdx.x;
  int i = blockIdx.x * 256 + t;
  int v = (i < NNODES) ? deg[i] : 0;
  s[t] = v;
  __syncthreads();
  for (int o = 1; o < 256; o <<= 1) {
    int x = (t >= o) ? s[t - o] : 0;
    __syncthreads();
    s[t] += x;
    __syncthreads();
  }
  if (i < NNODES) {
    int off = parts[blockIdx.x] + s[t] - v;
    offs[i] = off;
    curs[i] = off;
    dinv[i] = (v > 0) ? rsqrtf((float)v) : 0.f;
  }
  if (i == 0) offs[NNODES] = 2 * NEDGE;
}

// ---------------- CSR adjacency fill ----------------
__global__ void fill_kernel(const int* __restrict__ src, const int* __restrict__ dst,
                            int* __restrict__ curs, int* __restrict__ adj)
{
  int stride = gridDim.x * blockDim.x;
  for (int e = blockIdx.x * blockDim.x + threadIdx.x; e < NEDGE; e += stride) {
    int s = src[e];
    int d = NM + dst[e];
    adj[atomicAdd(&curs[d], 1)] = s;
    adj[atomicAdd(&curs[s], 1)] = d;
  }
}

// ---------------- LightGCN propagation (gather form) ----------------
__global__ __launch_bounds__(256) void prop_kernel(
    const float* __restrict__ xin, float* __restrict__ xout,
    const int* __restrict__ offs, const int* __restrict__ adj,
    const float* __restrict__ dinv, float* __restrict__ outA)
{
  const int v = blockIdx.x * 4 + (threadIdx.x >> 6);
  const int lane = threadIdx.x & 63;
  int p = offs[v];
  const int p1 = offs[v + 1];
  float ax = 0.f, ay = 0.f;
  const float* base = xin + 2 * lane;
  for (; p + 2 <= p1; p += 2) {
    int u0 = adj[p], u1 = adj[p + 1];
    float d0 = dinv[u0], d1 = dinv[u1];
    float2 r0 = *(const float2*)(base + (size_t)u0 * FEAT);
    float2 r1 = *(const float2*)(base + (size_t)u1 * FEAT);
    ax += r0.x * d0 + r1.x * d1;
    ay += r0.y * d0 + r1.y * d1;
  }
  if (p < p1) {
    int u0 = adj[p];
    float d0 = dinv[u0];
    float2 r0 = *(const float2*)(base + (size_t)u0 * FEAT);
    ax += r0.x * d0;
    ay += r0.y * d0;
  }
  const float dv = dinv[v];
  float2 res; res.x = ax * dv; res.y = ay * dv;
  *(float2*)(xout + (size_t)v * FEAT + 2 * lane) = res;
  if (v >= NM) {
    float2* o = (float2*)(outA + (size_t)(v - NM) * FEAT + 2 * lane);
    float2 c = *o;
    c.x += 0.25f * res.x;
    c.y += 0.25f * res.y;
    *o = c;
  }
}

// ---------------- pred = z_m[1024,128] @ O[50000,128]^T  (fp32, 128x128xK32 tile) ----
__global__ __launch_bounds__(256) void pred_kernel2(
    const float* __restrict__ zm, const float* __restrict__ O, float* __restrict__ out)
{
  __shared__ float Zs[32][132];  // [k][m]
  __shared__ float Os[32][132];  // [k][n]
  const int tid = threadIdx.x;
  const int nBase = blockIdx.x * 128;
  const int iBase = blockIdx.y * 128;
  const int ty = tid >> 4, tx = tid & 15;
  float acc[8][8];
  #pragma unroll
  for (int r = 0; r < 8; ++r)
    #pragma unroll
    for (int c = 0; c < 8; ++c) acc[r][c] = 0.f;

  const int sr = tid >> 3;        // 0..31
  const int kq = (tid & 7) * 4;   // 0,4,..,28

  for (int kt = 0; kt < 4; ++kt) {
    const int k0 = kt * 32;
    #pragma unroll
    for (int j = 0; j < 4; ++j) {
      int m = sr + 32 * j;
      float4 zv = *(const float4*)(zm + (size_t)(iBase + m) * FEAT + k0 + kq);
      Zs[kq + 0][m] = zv.x; Zs[kq + 1][m] = zv.y;
      Zs[kq + 2][m] = zv.z; Zs[kq + 3][m] = zv.w;
      int n = nBase + m; if (n > NA - 1) n = NA - 1;
      float4 ov = *(const float4*)(O + (size_t)n * FEAT + k0 + kq);
      Os[kq + 0][m] = ov.x; Os[kq + 1][m] = ov.y;
      Os[kq + 2][m] = ov.z; Os[kq + 3][m] = ov.w;
    }
    __syncthreads();
    #pragma unroll
    for (int kk = 0; kk < 32; ++kk) {
      float4 z0 = *(const float4*)&Zs[kk][ty * 4];
      float4 z1 = *(const float4*)&Zs[kk][64 + ty * 4];
      float4 o0 = *(const float4*)&Os[kk][tx * 4];
      float4 o1 = *(const float4*)&Os[kk][64 + tx * 4];
      float zz[8] = {z0.x, z0.y, z0.z, z0.w, z1.x, z1.y, z1.z, z1.w};
      float oo[8] = {o0.x, o0.y, o0.z, o0.w, o1.x, o1.y, o1.z, o1.w};
      #pragma unroll
      for (int r = 0; r < 8; ++r)
        #pragma unroll
        for (int c = 0; c < 8; ++c) acc[r][c] += zz[r] * oo[c];
    }
    __syncthreads();
  }

  #pragma unroll
  for (int r = 0; r < 8; ++r) {
    int row = iBase + ((r < 4) ? (ty * 4 + r) : (64 + ty * 4 + (r - 4)));
    #pragma unroll
    for (int h = 0; h < 2; ++h) {
      int ng = nBase + h * 64 + tx * 4;
      if (ng < NA) {
        float4 v = make_float4(acc[r][h * 4 + 0], acc[r][h * 4 + 1],
                               acc[r][h * 4 + 2], acc[r][h * 4 + 3]);
        *(float4*)(out + (size_t)row * NA + ng) = v;
      }
    }
  }
}

extern "C" void kernel_launch(void* const* d_in, const int* in_sizes, int n_in,
                              void* d_out, int out_size, void* d_ws, size_t ws_size,
                              hipStream_t stream) {
  const float* x      = (const float*)d_in[0];
  const float* mashup = (const float*)d_in[1];
  const float* domain = (const float*)d_in[2];
  const float* api    = (const float*)d_in[3];
  const float* Wsde   = (const float*)d_in[4];
  const float* bsde   = (const float*)d_in[5];
  const float* Wval   = (const float*)d_in[6];
  const float* bval   = (const float*)d_in[7];
  const float* Wkey   = (const float*)d_in[8];
  const float* bkey   = (const float*)d_in[9];
  const float* Wsie   = (const float*)d_in[10];
  const float* bsie   = (const float*)d_in[11];
  const int* esrc     = (const int*)d_in[12];
  const int* edst     = (const int*)d_in[13];
  float* out = (float*)d_out;

  // workspace layout
  float* ws   = (float*)d_ws;
  float* embA = ws;                                  // 100000*128
  float* embB = embA + (size_t)NNODES * FEAT;        // 100000*128
  float* outA = embB + (size_t)NNODES * FEAT;        // 50000*128
  float* vmi  = outA + (size_t)NA * FEAT;            // 1024*128
  float* vkey = vmi + (size_t)BATCH * FEAT;          // 500*128
  float* vval = vkey + (size_t)ND * FEAT;            // 500*128
  float* zm   = vval + (size_t)ND * FEAT;            // 1024*128
  float* dinv = zm + (size_t)BATCH * FEAT;           // 100000
  int* deg    = (int*)(dinv + NNODES);               // 100000
  int* offs   = deg + NNODES;                        // 100001
  int* curs   = offs + NNODES + 1;                   // 100000
  int* adj    = curs + NNODES;                       // 3200000
  int* parts  = adj + 2 * NEDGE;                     // 391 (pad to 400)
  bf16_t* wt0 = (bf16_t*)(parts + 400);              // 128*768 each
  bf16_t* wt1 = wt0 + (size_t)FEAT * KDIM;
  bf16_t* wt2 = wt1 + (size_t)FEAT * KDIM;
  bf16_t* wt3 = wt2 + (size_t)FEAT * KDIM;

  hipMemsetAsync(deg, 0, NNODES * sizeof(int), stream);

  wconv_kernel<<<FEAT, 256, 0, stream>>>(Wsde, wt0);
  wconv_kernel<<<FEAT, 256, 0, stream>>>(Wkey, wt1);
  wconv_kernel<<<FEAT, 256, 0, stream>>>(Wval, wt2);
  wconv_kernel<<<FEAT, 256, 0, stream>>>(Wsie, wt3);

  proj_mfma<<<(BATCH + 127) / 128, 256, 0, stream>>>(x, wt0, bsde, vmi, BATCH, nullptr);
  proj_mfma<<<(ND + 127) / 128, 256, 0, stream>>>(domain, wt1, bkey, vkey, ND, nullptr);
  proj_mfma<<<(ND + 127) / 128, 256, 0, stream>>>(domain, wt2, bval, vval, ND, nullptr);
  attn_kernel<<<BATCH, 256, 0, stream>>>(vmi, vkey, vval, zm);

  proj_mfma<<<(NM + 127) / 128, 256, 0, stream>>>(mashup, wt0, bsde, embA, NM, nullptr);
  proj_mfma<<<(NA + 127) / 128, 256, 0, stream>>>(api, wt3, bsie,
                                                  embA + (size_t)NM * FEAT, NA, outA);

  hist_kernel<<<2048, 256, 0, stream>>>(esrc, edst, deg);
  scan_blocksum<<<NPARTS, 256, 0, stream>>>(deg, parts);
  scan_parts<<<1, 512, 0, stream>>>(parts);
  scan_final<<<NPARTS, 256, 0, stream>>>(deg, parts, offs, curs, dinv);
  fill_kernel<<<2048, 256, 0, stream>>>(esrc, edst, curs, adj);

  prop_kernel<<<NNODES / 4, 256, 0, stream>>>(embA, embB, offs, adj, dinv, outA);
  prop_kernel<<<NNODES / 4, 256, 0, stream>>>(embB, embA, offs, adj, dinv, outA);
  prop_kernel<<<NNODES / 4, 256, 0, stream>>>(embA, embB, offs, adj, dinv, outA);

  pred_kernel2<<<dim3((NA + 127) / 128, BATCH / 128), 256, 0, stream>>>(zm, outA, out);
}

// Round 3
// 1007.358 us; speedup vs baseline: 2.2520x; 1.5522x over previous
//
#include <hip/hip_runtime.h>
#include <hip/hip_bf16.h>
#include <cstddef>
#include <cstdint>

#define NM 50000
#define NA 50000
#define ND 500
#define FEAT 128
#define KDIM 768
#define BATCH 1024
#define NEDGE 1600000
#define NNODES 100000
#define NPARTS 391   // ceil(100000/256)

typedef __bf16 bf16_t;
typedef bf16_t bf16x8 __attribute__((ext_vector_type(8)));
typedef bf16_t bf16x2 __attribute__((ext_vector_type(2)));
typedef float f32x4 __attribute__((ext_vector_type(4)));

__device__ __forceinline__ float sigf(float x) { return 1.0f / (1.0f + __expf(-x)); }

// ---------------- W[768,128] fp32 -> Wt[128,768] bf16 ----------------
__global__ __launch_bounds__(256) void wconv_kernel(const float* __restrict__ W,
                                                    bf16_t* __restrict__ Wt)
{
  int c = blockIdx.x;
  for (int k = threadIdx.x; k < KDIM; k += 256)
    Wt[(size_t)c * KDIM + k] = (bf16_t)W[(size_t)k * FEAT + c];
}

// ---------------- projection via MFMA: C = sigmoid(A[M,768] @ W[768,128] + b) ----
// BM=128, BN=128, BK=32, 4 waves (2x2), each wave 64x64 via 4x4 frags of 16x16x32.
template<bool BF16OUT>
__global__ __launch_bounds__(256) void proj_mfma(
    const float* __restrict__ A, const bf16_t* __restrict__ Wt,
    const float* __restrict__ bias, void* __restrict__ Cout, int M,
    float* __restrict__ C2 /* optional 0.25*sigmoid copy (fp32) */)
{
  __shared__ bf16x8 sm[1024];  // [0..511]=A frags, [512..1023]=B frags
  const int tid = threadIdx.x;
  const int rowBase = blockIdx.x * 128;
  const int lane = tid & 63;
  const int wid = tid >> 6;

  f32x4 acc[4][4];
  #pragma unroll
  for (int m = 0; m < 4; ++m)
    #pragma unroll
    for (int n = 0; n < 4; ++n)
      acc[m][n] = (f32x4){0.f, 0.f, 0.f, 0.f};

  const int rl0 = ((tid >> 6) << 4) + (tid & 15);
  const int k8 = (tid >> 4) & 3;

  for (int k0 = 0; k0 < KDIM; k0 += 32) {
    #pragma unroll
    for (int i = 0; i < 2; ++i) {
      int rloc = rl0 + 64 * i;
      int rg = rowBase + rloc;
      if (rg > M - 1) rg = M - 1;
      const float* ap = A + (size_t)rg * KDIM + k0 + k8 * 8;
      float4 v0 = *(const float4*)ap;
      float4 v1 = *(const float4*)(ap + 4);
      bf16x8 w;
      w[0] = (bf16_t)v0.x; w[1] = (bf16_t)v0.y; w[2] = (bf16_t)v0.z; w[3] = (bf16_t)v0.w;
      w[4] = (bf16_t)v1.x; w[5] = (bf16_t)v1.y; w[6] = (bf16_t)v1.z; w[7] = (bf16_t)v1.w;
      sm[tid + i * 256] = w;
      sm[512 + tid + i * 256] = *(const bf16x8*)(Wt + (size_t)rloc * KDIM + k0 + k8 * 8);
    }
    __syncthreads();
    bf16x8 a[4], b[4];
    const int fm = (wid >> 1) * 4, fn = (wid & 1) * 4;
    #pragma unroll
    for (int m = 0; m < 4; ++m) a[m] = sm[(fm + m) * 64 + lane];
    #pragma unroll
    for (int n = 0; n < 4; ++n) b[n] = sm[512 + (fn + n) * 64 + lane];
    #pragma unroll
    for (int m = 0; m < 4; ++m)
      #pragma unroll
      for (int n = 0; n < 4; ++n)
        acc[m][n] = __builtin_amdgcn_mfma_f32_16x16x32_bf16(a[m], b[n], acc[m][n], 0, 0, 0);
    __syncthreads();
  }

  // C frag layout: col=lane&15, row=(lane>>4)*4+reg
  const int wRow = (wid >> 1) * 64, wCol = (wid & 1) * 64;
  const int r0 = (lane >> 4) * 4, cc = lane & 15;
  #pragma unroll
  for (int n = 0; n < 4; ++n) {
    int col = wCol + n * 16 + cc;
    float bb = bias[col];
    #pragma unroll
    for (int m = 0; m < 4; ++m) {
      #pragma unroll
      for (int r = 0; r < 4; ++r) {
        int row = rowBase + wRow + m * 16 + r0 + r;
        if (row < M) {
          float v = sigf(acc[m][n][r] + bb);
          if constexpr (BF16OUT)
            ((bf16_t*)Cout)[(size_t)row * FEAT + col] = (bf16_t)v;
          else
            ((float*)Cout)[(size_t)row * FEAT + col] = v;
          if (C2) C2[(size_t)row * FEAT + col] = 0.25f * v;
        }
      }
    }
  }
}

// ---------------- attention ----------------
__global__ __launch_bounds__(256) void attn_kernel(
    const float* __restrict__ vmi, const float* __restrict__ vkey,
    const float* __restrict__ vval, bf16_t* __restrict__ zm)
{
  const int i = blockIdx.x;
  const int tid = threadIdx.x;
  __shared__ float vs[FEAT];
  __shared__ float al[ND];
  __shared__ float red[4];
  __shared__ float totS;
  if (tid < FEAT) vs[tid] = vmi[(size_t)i * FEAT + tid];
  __syncthreads();
  float part = 0.f;
  for (int j = tid; j < ND; j += 256) {
    const float* kr = vkey + (size_t)j * FEAT;
    float dot = 0.f;
    #pragma unroll 8
    for (int k = 0; k < FEAT; k += 4) {
      float4 kv = *(const float4*)(kr + k);
      dot += vs[k] * kv.x + vs[k + 1] * kv.y + vs[k + 2] * kv.z + vs[k + 3] * kv.w;
    }
    al[j] = dot;
    part += dot;
  }
  #pragma unroll
  for (int o = 32; o > 0; o >>= 1) part += __shfl_down(part, o, 64);
  if ((tid & 63) == 0) red[tid >> 6] = part;
  __syncthreads();
  if (tid == 0) totS = red[0] + red[1] + red[2] + red[3];
  __syncthreads();
  const float inv = 1.0f / totS;
  if (tid < FEAT) {
    float s = 0.f;
    #pragma unroll 4
    for (int j = 0; j < ND; ++j) s += al[j] * vval[(size_t)j * FEAT + tid];
    float z = 0.5f * (s * inv + vs[tid]);
    zm[(size_t)i * FEAT + tid] = (bf16_t)z;
  }
}

// ---------------- degree histogram ----------------
__global__ void hist_kernel(const int* __restrict__ src, const int* __restrict__ dst,
                            int* __restrict__ deg)
{
  int stride = gridDim.x * blockDim.x;
  for (int e = blockIdx.x * blockDim.x + threadIdx.x; e < NEDGE; e += stride) {
    atomicAdd(&deg[src[e]], 1);
    atomicAdd(&deg[NM + dst[e]], 1);
  }
}

// ---------------- scan step A ----------------
__global__ __launch_bounds__(256) void scan_blocksum(const int* __restrict__ deg,
                                                     int* __restrict__ parts)
{
  int i = blockIdx.x * 256 + threadIdx.x;
  int v = (i < NNODES) ? deg[i] : 0;
  __shared__ int red[4];
  #pragma unroll
  for (int o = 32; o > 0; o >>= 1) v += __shfl_down(v, o, 64);
  if ((threadIdx.x & 63) == 0) red[threadIdx.x >> 6] = v;
  __syncthreads();
  if (threadIdx.x == 0) parts[blockIdx.x] = red[0] + red[1] + red[2] + red[3];
}

// ---------------- scan step B ----------------
__global__ __launch_bounds__(512) void scan_parts(int* __restrict__ parts)
{
  __shared__ int s[512];
  int t = threadIdx.x;
  int v = (t < NPARTS) ? parts[t] : 0;
  s[t] = v;
  __syncthreads();
  for (int o = 1; o < 512; o <<= 1) {
    int x = (t >= o) ? s[t - o] : 0;
    __syncthreads();
    s[t] += x;
    __syncthreads();
  }
  if (t < NPARTS) parts[t] = s[t] - v;  // exclusive
}

// ---------------- scan step C ----------------
__global__ __launch_bounds__(256) void scan_final(const int* __restrict__ deg,
                                                  const int* __restrict__ parts,
                                                  int* __restrict__ offs,
                                                  int* __restrict__ curs,
                                                  float* __restrict__ dinv)
{
  __shared__ int s[256];
  int t = threadIdx.x;
  int i = blockIdx.x * 256 + t;
  int v = (i < NNODES) ? deg[i] : 0;
  s[t] = v;
  __syncthreads();
  for (int o = 1; o < 256; o <<= 1) {
    int x = (t >= o) ? s[t - o] : 0;
    __syncthreads();
    s[t] += x;
    __syncthreads();
  }
  if (i < NNODES) {
    int off = parts[blockIdx.x] + s[t] - v;
    offs[i] = off;
    curs[i] = off;
    dinv[i] = (v > 0) ? rsqrtf((float)v) : 0.f;
  }
  if (i == 0) offs[NNODES] = 2 * NEDGE;
}

// ---------------- CSR fill, XCD-partitioned ----------------
// blockIdx%8 ~ XCD (perf-only heuristic); each XCD owns 1/8 of mashup + api node
// ranges so adj cache lines are dirtied by exactly one XCD L2 -> lines fill before
// eviction (kills the 16x write amplification). Each XCD group scans all edges.
__global__ __launch_bounds__(256) void fill_part(const int* __restrict__ src,
                                                 const int* __restrict__ dst,
                                                 int* __restrict__ curs,
                                                 int* __restrict__ adj)
{
  const int x = blockIdx.x & 7;
  const int grp = blockIdx.x >> 3;         // 0..255
  const int mlo = x * (NM / 8), mhi = mlo + (NM / 8);
  const int alo = x * (NA / 8), ahi = alo + (NA / 8);
  const int ebase = grp * (NEDGE / 256);
  const int eend = ebase + (NEDGE / 256);
  for (int e = ebase + threadIdx.x; e < eend; e += 256) {
    int s = src[e], d = dst[e];
    if (s >= mlo && s < mhi) adj[atomicAdd(&curs[s], 1)] = NM + d;
    if (d >= alo && d < ahi) adj[atomicAdd(&curs[NM + d], 1)] = s;
  }
}

// ---------------- LightGCN propagation, bf16 emb (gather form) ----------------
__global__ __launch_bounds__(256) void prop_bf16(
    const bf16_t* __restrict__ xin, bf16_t* __restrict__ xout,
    const int* __restrict__ offs, const int* __restrict__ adj,
    const float* __restrict__ dinv, float* __restrict__ outA)
{
  const int v = blockIdx.x * 4 + (threadIdx.x >> 6);
  const int lane = threadIdx.x & 63;
  int p = offs[v];
  const int p1 = offs[v + 1];
  float ax = 0.f, ay = 0.f;
  const uint32_t* base = (const uint32_t*)xin + lane;  // row stride = 64 dwords
  for (; p + 4 <= p1; p += 4) {
    int u0 = adj[p], u1 = adj[p + 1], u2 = adj[p + 2], u3 = adj[p + 3];
    float d0 = dinv[u0], d1 = dinv[u1], d2 = dinv[u2], d3 = dinv[u3];
    uint32_t w0 = base[(size_t)u0 * 64], w1 = base[(size_t)u1 * 64];
    uint32_t w2 = base[(size_t)u2 * 64], w3 = base[(size_t)u3 * 64];
    ax += __uint_as_float(w0 << 16) * d0 + __uint_as_float(w1 << 16) * d1 +
          __uint_as_float(w2 << 16) * d2 + __uint_as_float(w3 << 16) * d3;
    ay += __uint_as_float(w0 & 0xffff0000u) * d0 + __uint_as_float(w1 & 0xffff0000u) * d1 +
          __uint_as_float(w2 & 0xffff0000u) * d2 + __uint_as_float(w3 & 0xffff0000u) * d3;
  }
  for (; p < p1; ++p) {
    int u0 = adj[p];
    float d0 = dinv[u0];
    uint32_t w0 = base[(size_t)u0 * 64];
    ax += __uint_as_float(w0 << 16) * d0;
    ay += __uint_as_float(w0 & 0xffff0000u) * d0;
  }
  const float dv = dinv[v];
  float rx = ax * dv, ry = ay * dv;
  bf16x2 pk; pk[0] = (bf16_t)rx; pk[1] = (bf16_t)ry;
  *(bf16x2*)((bf16_t*)xout + (size_t)v * FEAT + 2 * lane) = pk;
  if (v >= NM) {
    float2* o = (float2*)(outA + (size_t)(v - NM) * FEAT + 2 * lane);
    float2 c = *o;
    c.x += 0.25f * rx;
    c.y += 0.25f * ry;
    *o = c;
  }
}

// ---------------- last layer: api nodes only, fused final O (bf16) ----------------
__global__ __launch_bounds__(256) void prop_last(
    const bf16_t* __restrict__ xin, const float* __restrict__ outA,
    bf16_t* __restrict__ Obf,
    const int* __restrict__ offs, const int* __restrict__ adj,
    const float* __restrict__ dinv)
{
  const int i = blockIdx.x * 4 + (threadIdx.x >> 6);  // api index
  const int v = NM + i;
  const int lane = threadIdx.x & 63;
  int p = offs[v];
  const int p1 = offs[v + 1];
  float ax = 0.f, ay = 0.f;
  const uint32_t* base = (const uint32_t*)xin + lane;
  for (; p + 4 <= p1; p += 4) {
    int u0 = adj[p], u1 = adj[p + 1], u2 = adj[p + 2], u3 = adj[p + 3];
    float d0 = dinv[u0], d1 = dinv[u1], d2 = dinv[u2], d3 = dinv[u3];
    uint32_t w0 = base[(size_t)u0 * 64], w1 = base[(size_t)u1 * 64];
    uint32_t w2 = base[(size_t)u2 * 64], w3 = base[(size_t)u3 * 64];
    ax += __uint_as_float(w0 << 16) * d0 + __uint_as_float(w1 << 16) * d1 +
          __uint_as_float(w2 << 16) * d2 + __uint_as_float(w3 << 16) * d3;
    ay += __uint_as_float(w0 & 0xffff0000u) * d0 + __uint_as_float(w1 & 0xffff0000u) * d1 +
          __uint_as_float(w2 & 0xffff0000u) * d2 + __uint_as_float(w3 & 0xffff0000u) * d3;
  }
  for (; p < p1; ++p) {
    int u0 = adj[p];
    float d0 = dinv[u0];
    uint32_t w0 = base[(size_t)u0 * 64];
    ax += __uint_as_float(w0 << 16) * d0;
    ay += __uint_as_float(w0 & 0xffff0000u) * d0;
  }
  const float dv = dinv[v];
  const float2 prev = *(const float2*)(outA + (size_t)i * FEAT + 2 * lane);
  bf16x2 pk;
  pk[0] = (bf16_t)(prev.x + 0.25f * ax * dv);
  pk[1] = (bf16_t)(prev.y + 0.25f * ay * dv);
  *(bf16x2*)(Obf + (size_t)i * FEAT + 2 * lane) = pk;
}

// ---------------- pred = Z[1024,128] @ O[50000,128]^T, bf16 MFMA ----------------
// 256 threads = 4 waves; block tile 64 x 256 (wave tile 64x64, 4x4 frags), K=128.
__global__ __launch_bounds__(256) void pred_mfma(
    const bf16_t* __restrict__ Z, const bf16_t* __restrict__ O,
    float* __restrict__ out)
{
  const int lane = threadIdx.x & 63;
  const int wid = threadIdx.x >> 6;
  const int iBase = blockIdx.y * 64;
  const int nBase = blockIdx.x * 256 + wid * 64;
  const int rA = iBase + (lane & 15);
  const int kOff = (lane >> 4) * 8;

  f32x4 acc[4][4];
  #pragma unroll
  for (int m = 0; m < 4; ++m)
    #pragma unroll
    for (int n = 0; n < 4; ++n)
      acc[m][n] = (f32x4){0.f, 0.f, 0.f, 0.f};

  #pragma unroll
  for (int kk = 0; kk < 4; ++kk) {
    bf16x8 a[4], b[4];
    #pragma unroll
    for (int m = 0; m < 4; ++m)
      a[m] = *(const bf16x8*)(Z + (size_t)(rA + m * 16) * FEAT + kk * 32 + kOff);
    #pragma unroll
    for (int n = 0; n < 4; ++n) {
      int c = nBase + n * 16 + (lane & 15);
      if (c > NA - 1) c = NA - 1;
      b[n] = *(const bf16x8*)(O + (size_t)c * FEAT + kk * 32 + kOff);
    }
    #pragma unroll
    for (int m = 0; m < 4; ++m)
      #pragma unroll
      for (int n = 0; n < 4; ++n)
        acc[m][n] = __builtin_amdgcn_mfma_f32_16x16x32_bf16(a[m], b[n], acc[m][n], 0, 0, 0);
  }

  const int r0 = (lane >> 4) * 4, cc = lane & 15;
  #pragma unroll
  for (int n = 0; n < 4; ++n) {
    int col = nBase + n * 16 + cc;
    if (col < NA) {
      #pragma unroll
      for (int m = 0; m < 4; ++m) {
        #pragma unroll
        for (int r = 0; r < 4; ++r) {
          int row = iBase + m * 16 + r0 + r;
          out[(size_t)row * NA + col] = acc[m][n][r];
        }
      }
    }
  }
}

static inline char* alignup(char* p, size_t a) {
  return (char*)(((uintptr_t)p + a - 1) & ~(uintptr_t)(a - 1));
}

extern "C" void kernel_launch(void* const* d_in, const int* in_sizes, int n_in,
                              void* d_out, int out_size, void* d_ws, size_t ws_size,
                              hipStream_t stream) {
  const float* x      = (const float*)d_in[0];
  const float* mashup = (const float*)d_in[1];
  const float* domain = (const float*)d_in[2];
  const float* api    = (const float*)d_in[3];
  const float* Wsde   = (const float*)d_in[4];
  const float* bsde   = (const float*)d_in[5];
  const float* Wval   = (const float*)d_in[6];
  const float* bval   = (const float*)d_in[7];
  const float* Wkey   = (const float*)d_in[8];
  const float* bkey   = (const float*)d_in[9];
  const float* Wsie   = (const float*)d_in[10];
  const float* bsie   = (const float*)d_in[11];
  const int* esrc     = (const int*)d_in[12];
  const int* edst     = (const int*)d_in[13];
  float* out = (float*)d_out;

  // workspace layout
  char* p = (char*)d_ws;
  bf16_t* embA = (bf16_t*)p; p += (size_t)NNODES * FEAT * 2;      // 25.6MB
  bf16_t* embB = (bf16_t*)p; p += (size_t)NNODES * FEAT * 2;      // 25.6MB
  float*  outA = (float*)p;  p += (size_t)NA * FEAT * 4;          // 25.6MB
  bf16_t* Obf  = (bf16_t*)p; p += (size_t)NA * FEAT * 2;          // 12.8MB
  float*  vmi  = (float*)p;  p += (size_t)BATCH * FEAT * 4;
  float*  vkey = (float*)p;  p += (size_t)ND * FEAT * 4;
  float*  vval = (float*)p;  p += (size_t)ND * FEAT * 4;
  bf16_t* zm   = (bf16_t*)p; p += (size_t)BATCH * FEAT * 2;
  float*  dinv = (float*)p;  p += (size_t)NNODES * 4;
  int* deg  = (int*)p; p += (size_t)NNODES * 4;
  int* offs = (int*)p; p += (size_t)(NNODES + 4) * 4;
  int* curs = (int*)p; p += (size_t)NNODES * 4;
  int* adj  = (int*)p; p += (size_t)2 * NEDGE * 4;
  int* parts = (int*)p; p += 512 * 4;
  p = alignup(p, 16);
  bf16_t* wt0 = (bf16_t*)p; p += (size_t)FEAT * KDIM * 2;
  bf16_t* wt1 = (bf16_t*)p; p += (size_t)FEAT * KDIM * 2;
  bf16_t* wt2 = (bf16_t*)p; p += (size_t)FEAT * KDIM * 2;
  bf16_t* wt3 = (bf16_t*)p; p += (size_t)FEAT * KDIM * 2;

  hipMemsetAsync(deg, 0, NNODES * sizeof(int), stream);

  wconv_kernel<<<FEAT, 256, 0, stream>>>(Wsde, wt0);
  wconv_kernel<<<FEAT, 256, 0, stream>>>(Wkey, wt1);
  wconv_kernel<<<FEAT, 256, 0, stream>>>(Wval, wt2);
  wconv_kernel<<<FEAT, 256, 0, stream>>>(Wsie, wt3);

  proj_mfma<false><<<(BATCH + 127) / 128, 256, 0, stream>>>(x, wt0, bsde, vmi, BATCH, nullptr);
  proj_mfma<false><<<(ND + 127) / 128, 256, 0, stream>>>(domain, wt1, bkey, vkey, ND, nullptr);
  proj_mfma<false><<<(ND + 127) / 128, 256, 0, stream>>>(domain, wt2, bval, vval, ND, nullptr);
  attn_kernel<<<BATCH, 256, 0, stream>>>(vmi, vkey, vval, zm);

  proj_mfma<true><<<(NM + 127) / 128, 256, 0, stream>>>(mashup, wt0, bsde, embA, NM, nullptr);
  proj_mfma<true><<<(NA + 127) / 128, 256, 0, stream>>>(api, wt3, bsie,
                                                        embA + (size_t)NM * FEAT, NA, outA);

  hist_kernel<<<2048, 256, 0, stream>>>(esrc, edst, deg);
  scan_blocksum<<<NPARTS, 256, 0, stream>>>(deg, parts);
  scan_parts<<<1, 512, 0, stream>>>(parts);
  scan_final<<<NPARTS, 256, 0, stream>>>(deg, parts, offs, curs, dinv);
  fill_part<<<2048, 256, 0, stream>>>(esrc, edst, curs, adj);

  prop_bf16<<<NNODES / 4, 256, 0, stream>>>(embA, embB, offs, adj, dinv, outA);
  prop_bf16<<<NNODES / 4, 256, 0, stream>>>(embB, embA, offs, adj, dinv, outA);
  prop_last<<<NA / 4, 256, 0, stream>>>(embA, outA, Obf, offs, adj, dinv);

  pred_mfma<<<dim3((NA + 255) / 256, BATCH / 64), 256, 0, stream>>>(zm, Obf, out);
}